// Round 11
// baseline (522.086 us; speedup 1.0000x reference)
//
#include <hip/hip_runtime.h>
#include <hip/hip_bf16.h>

typedef __bf16 bf16_t;
typedef __bf16 bf16x4_t __attribute__((ext_vector_type(4)));
typedef __bf16 bf16x8 __attribute__((ext_vector_type(8)));
typedef float f32x16 __attribute__((ext_vector_type(16)));

#define MFMA32(a, b, c) __builtin_amdgcn_mfma_f32_32x32x16_bf16(a, b, c, 0, 0, 0)

// ---------------- one-time weight conversion (verified r4-r10) ------------
// W1t [128 j][1024 i] bf16 (for gemm_A).
// W2B frag-major (C-pass A-operand): idx = ((jt*64+s)*64+lane)*8+e
//     element = W2[jt*32+(lane&31)][s*16+(lane>>5)*8+e]   (0 if k>=1000)
// W2T frag-major (D-pass A-operand): idx = ((kt*8+js)*64+lane)*8+e
//     element = W2[js*16+(lane>>5)*8+e][kt*32+(lane&31)]  (0 if k>=1000)
__global__ __launch_bounds__(256) void prep_weights(
    const float* __restrict__ W1, const float* __restrict__ W2,
    bf16_t* __restrict__ W1t, bf16_t* __restrict__ W2B, bf16_t* __restrict__ W2T) {
  int idx = blockIdx.x * 256 + threadIdx.x;
  if (idx < 131072) {
    { int j = idx >> 10, i = idx & 1023; W1t[idx] = (bf16_t)W1[i * 128 + j]; }
    { int e = idx & 7, l = (idx >> 3) & 63, s = (idx >> 9) & 63, jt = idx >> 15;
      int j = jt * 32 + (l & 31), k = s * 16 + (l >> 5) * 8 + e;
      W2B[idx] = (bf16_t)((k < 1000) ? W2[j * 1000 + k] : 0.f); }
    { int e = idx & 7, l = (idx >> 3) & 63, js = (idx >> 9) & 7, kt = idx >> 12;
      int k = kt * 32 + (l & 31), j = js * 16 + (l >> 5) * 8 + e;
      W2T[idx] = (bf16_t)((k < 1000) ? W2[j * 1000 + k] : 0.f); }
  }
}

// ---------------- A = x @ W1 (f32 out), 256 blocks (verified r8-r10) ------
__global__ __launch_bounds__(256) void gemm_A(
    const float* __restrict__ x, const bf16_t* __restrict__ W1t,
    float* __restrict__ A) {
  int lane = threadIdx.x & 63, w = threadIdx.x >> 6;
  int lo = lane & 31, hi = lane >> 5;
  int row0 = blockIdx.x * 32;
  f32x16 acc = {};
  int kg = hi * 8;
  const float* xrow = x + (size_t)(row0 + lo) * 1024 + kg;
  const bf16_t* b0 = W1t + ((w * 32 + lo) << 10) + kg;
#pragma unroll 4
  for (int ks = 0; ks < 64; ++ks) {
    float xv[8];
    *(float4*)&xv[0] = *(const float4*)(xrow + ks * 16);
    *(float4*)&xv[4] = *(const float4*)(xrow + ks * 16 + 4);
    bf16x8 a;
#pragma unroll
    for (int i = 0; i < 8; ++i) a[i] = (bf16_t)xv[i];
    bf16x8 f0 = *(const bf16x8*)(b0 + ks * 16);
    acc = MFMA32(a, f0, acc);
  }
#pragma unroll
  for (int reg = 0; reg < 16; ++reg) {
    int r = (reg & 3) + 8 * (reg >> 2) + 4 * hi;
    A[(size_t)(row0 + r) * 128 + w * 32 + lo] = acc[reg];
  }
}

// state update: n = clip(v - eps*rho'*(v - u)); JAX clip tie-grad 0.5 at {0,1}
__device__ __forceinline__ bf16x4_t upd4(bf16x4_t v4, const float* u) {
  bf16x4_t n4;
#pragma unroll
  for (int r = 0; r < 4; ++r) {
    float v = (float)v4[r];
    float g = __builtin_fmaf(v, v, -v);          // 0 iff v in {0,1}
    float st = (g == 0.f) ? 0.25f : 0.5f;        // eps * rho'
    float n = __builtin_fmaf(-st, v - u[r], v);
    n4[r] = (bf16_t)__builtin_amdgcn_fmed3f(n, 0.f, 1.f);
  }
  return n4;
}

// ---------------- persistent relaxation + log_softmax ----------------
// 256 blocks x 1024 threads (16 waves, 1 block/CU). True reg budget per
// wave: 64 arch-VGPR + 64 AGPR (weights + acc live in AGPR; staging/temps
// in VGPR). Frag-major LDS. o SINGLE-buffered; h double-buffered; W2T
// ktiles 12-19 parked in LDS (iteration-invariant). 2 barriers/iter:
// [compute: C reads o, D reads h/o, C writes h^1] B1 [D writes o] B2.
// C-waves 0-3: jt=w, 8 frags resident-AGPR + 56 streamed (14x4 parity).
// D-waves 4-15: streamed ktile 20+wd (h from LDS), resident ktile wd
// (hf in regs), wlds ktile 12+wd (wd<8); new-o in regs across B1.
__global__ __launch_bounds__(1024, 4) void eqprop(
    const float* __restrict__ h0, const float* __restrict__ o0,
    const float* __restrict__ b_h, const float* __restrict__ b_o,
    const float* __restrict__ A, const bf16_t* __restrict__ W2B,
    const bf16_t* __restrict__ W2T, const int* __restrict__ nit,
    float* __restrict__ out) {
  __shared__ __align__(16) char o_raw[65536];   // o state, frag-major, single
  __shared__ __align__(16) char h_raw[16384];   // h state, 2 x 8 KB
  __shared__ __align__(16) char wlds[65536];    // W2T ktiles 12..19
  __shared__ float bo_lds[1024];

  const int tid = threadIdx.x, lane = tid & 63, w = tid >> 6;
  const int lo = lane & 31, hi = lane >> 5;
  const int row0 = blockIdx.x * 32;

  // ---- init: o (frag-major), h[0], wlds weight bank, bo table
  for (int idx = tid; idx < 32768; idx += 1024) {
    int b = idx >> 10, k = idx & 1023;
    float v = (k < 1000) ? o0[(size_t)(row0 + b) * 1000 + k] : 0.f;
    int ad = ((k >> 4) << 10) + ((((k >> 3) & 1) << 5) + b) * 16 + ((k & 7) << 1);
    *(bf16_t*)(o_raw + ad) = (bf16_t)v;
  }
  for (int idx = tid; idx < 4096; idx += 1024) {
    int b = idx >> 7, j = idx & 127;
    int ad = ((j >> 4) << 10) + ((((j >> 3) & 1) << 5) + b) * 16 + ((j & 7) << 1);
    *(bf16_t*)(h_raw + ad) = (bf16_t)h0[(size_t)(row0 + b) * 128 + j];
  }
#pragma unroll
  for (int c = 0; c < 4; ++c)   // 64 KB = ktiles 12..19 of W2T
    ((uint4*)wlds)[tid + c * 1024] = ((const uint4*)(W2T + 49152))[tid + c * 1024];
  bo_lds[tid] = (tid < 1000) ? b_o[tid] : 0.f;

  const int T = nit[0];
  int p = 0;
  __syncthreads();

  if (w < 4) {
    // ============ C-waves: Ct[j,b] = sum_k W2[j,k] o[b,k], jt = w =========
    const int jt = w;
    const bf16_t* WB = W2B + (size_t)jt * 32768 + lane * 8;
#define CW(s) (*(const bf16x8*)(WB + (s) * 512))
    bf16x8 wres[8];
#pragma unroll
    for (int s = 0; s < 8; ++s) wres[s] = CW(s);
    const char* obase = o_raw + lane * 16;
#define OF(s) (*(const bf16x8*)(obase + (s) * 1024))

    for (int t = 0; t < T; ++t) {
      f32x16 acc = {};
#pragma unroll
      for (int s = 0; s < 8; ++s) acc = MFMA32(wres[s], OF(s), acc);
      // streamed k-steps 8..63: 14 batches of 4, unroll-1 parity loop
      bf16x8 cs0[4], cs1[4];
      cs0[0] = CW(8); cs0[1] = CW(9); cs0[2] = CW(10); cs0[3] = CW(11);
#pragma unroll 1
      for (int c = 0; c < 14; ++c) {
        const int s0 = 8 + c * 4;
        if ((c & 1) == 0) {
          if (c < 13) {
            cs1[0] = CW(s0 + 4); cs1[1] = CW(s0 + 5);
            cs1[2] = CW(s0 + 6); cs1[3] = CW(s0 + 7);
          }
          acc = MFMA32(cs0[0], OF(s0 + 0), acc);
          acc = MFMA32(cs0[1], OF(s0 + 1), acc);
          acc = MFMA32(cs0[2], OF(s0 + 2), acc);
          acc = MFMA32(cs0[3], OF(s0 + 3), acc);
        } else {
          if (c < 13) {
            cs0[0] = CW(s0 + 4); cs0[1] = CW(s0 + 5);
            cs0[2] = CW(s0 + 6); cs0[3] = CW(s0 + 7);
          }
          acc = MFMA32(cs1[0], OF(s0 + 0), acc);
          acc = MFMA32(cs1[1], OF(s0 + 1), acc);
          acc = MFMA32(cs1[2], OF(s0 + 2), acc);
          acc = MFMA32(cs1[3], OF(s0 + 3), acc);
        }
      }
      // ---- h-update (pre-B1; writes h^(p^1), reads h^p own slice only)
      const char* hrd = h_raw + (p << 13) + lo * 16 + hi * 8;
      char* hwr = h_raw + ((p ^ 1) << 13) + lo * 16 + hi * 8;
#pragma unroll
      for (int q = 0; q < 4; ++q) {
        const int jb = jt * 32 + q * 8 + 4 * hi;
        const int boff = (jt * 2 + (q >> 1)) * 1024 + (q & 1) * 512;
        float av[4], bh[4], u[4];
        *(float4*)av = *(const float4*)(A + (size_t)(row0 + lo) * 128 + jb);
        *(float4*)bh = *(const float4*)(b_h + jb);
#pragma unroll
        for (int r = 0; r < 4; ++r) u[r] = av[r] + bh[r] + acc[q * 4 + r];
        bf16x4_t v4 = *(const bf16x4_t*)(hrd + boff);
        *(bf16x4_t*)(hwr + boff) = upd4(v4, u);
      }
      __syncthreads();  // B1: o-reads complete
      __syncthreads();  // B2: D's o-writes complete
      p ^= 1;
    }
  } else {
    // ============ D-waves: Dt[k,b] = sum_j W2[j,k] h[b,j] =================
    const int wd = w - 4;                    // 0..11
    const int ktS = 20 + wd;                 // streamed from L2
    const bool hasW = (wd < 8);
    const int ktW = 12 + wd;                 // from wlds
    const bf16_t* WTs = W2T + (size_t)ktS * 4096 + lane * 8;
    const bf16_t* WTr = W2T + (size_t)wd * 4096 + lane * 8;
    bf16x8 wres[8];                          // resident ktile wd (AGPR)
#pragma unroll
    for (int f = 0; f < 8; ++f) wres[f] = *(const bf16x8*)(WTr + f * 512);
    const char* wl = wlds + wd * 8192 + lane * 16;
    const char* ob = o_raw + lo * 16 + hi * 8;
    char* ow = o_raw + lo * 16 + hi * 8;

#define MAKE_NO(kt, accv, no)                                              \
  {                                                                        \
    _Pragma("unroll") for (int q = 0; q < 4; ++q) {                        \
      const int boff = ((kt) * 2 + (q >> 1)) * 1024 + (q & 1) * 512;       \
      float u[4];                                                          \
      *(float4*)u = *(const float4*)(bo_lds + (kt) * 32 + q * 8 + 4 * hi); \
      u[0] += accv[q * 4 + 0]; u[1] += accv[q * 4 + 1];                    \
      u[2] += accv[q * 4 + 2]; u[3] += accv[q * 4 + 3];                    \
      bf16x4_t v4 = *(const bf16x4_t*)(ob + boff);                         \
      no[q] = upd4(v4, u);                                                 \
    }                                                                      \
  }
#define STORE_NO(kt, no)                                                   \
  {                                                                        \
    _Pragma("unroll") for (int q = 0; q < 4; ++q) {                        \
      const int boff = ((kt) * 2 + (q >> 1)) * 1024 + (q & 1) * 512;       \
      *(bf16x4_t*)(ow + boff) = no[q];                                     \
    }                                                                      \
  }
#define HF(js) (*(const bf16x8*)(hp + (js) * 1024))

    for (int t = 0; t < T; ++t) {
      const char* hp = h_raw + (p << 13) + lane * 16;
      bf16x4_t noS[4], noR[4], noW[4];
      // ---- streamed ktile FIRST (h from LDS; low VGPR phase)
      {
        f32x16 acc = {};
        bf16x8 s0 = *(const bf16x8*)(WTs + 0 * 512);
        bf16x8 s1 = *(const bf16x8*)(WTs + 1 * 512);
        bf16x8 s2 = *(const bf16x8*)(WTs + 2 * 512);
        bf16x8 s3 = *(const bf16x8*)(WTs + 3 * 512);
        acc = MFMA32(s0, HF(0), acc);
        acc = MFMA32(s1, HF(1), acc);
        bf16x8 s4 = *(const bf16x8*)(WTs + 4 * 512);
        bf16x8 s5 = *(const bf16x8*)(WTs + 5 * 512);
        acc = MFMA32(s2, HF(2), acc);
        acc = MFMA32(s3, HF(3), acc);
        bf16x8 s6 = *(const bf16x8*)(WTs + 6 * 512);
        bf16x8 s7 = *(const bf16x8*)(WTs + 7 * 512);
        acc = MFMA32(s4, HF(4), acc);
        acc = MFMA32(s5, HF(5), acc);
        acc = MFMA32(s6, HF(6), acc);
        acc = MFMA32(s7, HF(7), acc);
        MAKE_NO(ktS, acc, noS);
      }
      // ---- resident ktile (h fragments into registers, reused by wlds)
      bf16x8 hf[8];
#pragma unroll
      for (int js = 0; js < 8; ++js) hf[js] = HF(js);
      {
        f32x16 acc = {};
#pragma unroll
        for (int js = 0; js < 8; ++js) acc = MFMA32(wres[js], hf[js], acc);
        MAKE_NO(wd, acc, noR);
      }
      // ---- wlds ktile (weights from LDS, base+imm)
      if (hasW) {
        f32x16 acc = {};
#pragma unroll
        for (int js = 0; js < 8; ++js) {
          bf16x8 wf = *(const bf16x8*)(wl + js * 1024);
          acc = MFMA32(wf, hf[js], acc);
        }
        MAKE_NO(ktW, acc, noW);
      }
      __syncthreads();  // B1: C-waves' o-reads complete
      STORE_NO(ktS, noS);
      STORE_NO(wd, noR);
      if (hasW) STORE_NO(ktW, noW);
      __syncthreads();  // B2: o consistent for next iteration
      p ^= 1;
    }
  }
  __syncthreads();

  // ---- epilogue: log_softmax per row (2 rows per wave)
  for (int row = w * 2; row < w * 2 + 2; ++row) {
    float m = -1e30f;
    for (int k = lane; k < 1000; k += 64) {
      int ad = ((k >> 4) << 10) + ((((k >> 3) & 1) << 5) + row) * 16 + ((k & 7) << 1);
      m = fmaxf(m, (float)*(const bf16_t*)(o_raw + ad));
    }
#pragma unroll
    for (int s = 32; s > 0; s >>= 1) m = fmaxf(m, __shfl_xor(m, s));
    float sum = 0.f;
    for (int k = lane; k < 1000; k += 64) {
      int ad = ((k >> 4) << 10) + ((((k >> 3) & 1) << 5) + row) * 16 + ((k & 7) << 1);
      sum += expf((float)*(const bf16_t*)(o_raw + ad) - m);
    }
#pragma unroll
    for (int s = 32; s > 0; s >>= 1) sum += __shfl_xor(sum, s);
    float lse = m + logf(sum);
    for (int k = lane; k < 1000; k += 64) {
      int ad = ((k >> 4) << 10) + ((((k >> 3) & 1) << 5) + row) * 16 + ((k & 7) << 1);
      out[(size_t)(row0 + row) * 1000 + k] =
          (float)*(const bf16_t*)(o_raw + ad) - lse;
    }
  }
}

extern "C" void kernel_launch(void* const* d_in, const int* in_sizes, int n_in,
                              void* d_out, int out_size, void* d_ws, size_t ws_size,
                              hipStream_t stream) {
  const float* x   = (const float*)d_in[0];
  const float* h0  = (const float*)d_in[1];
  const float* o0  = (const float*)d_in[2];
  // d_in[3] = b_in: unused by the h/o gradients
  const float* b_h = (const float*)d_in[4];
  const float* b_o = (const float*)d_in[5];
  const float* W1  = (const float*)d_in[6];
  const float* W2  = (const float*)d_in[7];
  const int*   nit = (const int*)d_in[8];
  float* out = (float*)d_out;

  char* ws = (char*)d_ws;
  float*  A   = (float*)ws;                           // 8192*128*4 = 4 MB
  bf16_t* W1t = (bf16_t*)(ws + 4194304);              // 256 KB
  bf16_t* W2B = (bf16_t*)(ws + 4194304 + 262144);     // 256 KB
  bf16_t* W2T = (bf16_t*)(ws + 4194304 + 524288);     // 256 KB

  prep_weights<<<512, 256, 0, stream>>>(W1, W2, W1t, W2B, W2T);
  gemm_A<<<256, 256, 0, stream>>>(x, W1t, A);
  eqprop<<<256, 1024, 0, stream>>>(h0, o0, b_h, b_o, A, W2B, W2T, nit, out);
}

// Round 12
// 249.044 us; speedup vs baseline: 2.0964x; 2.0964x over previous
//
#include <hip/hip_runtime.h>
#include <hip/hip_bf16.h>

typedef __bf16 bf16_t;
typedef __bf16 bf16x4_t __attribute__((ext_vector_type(4)));
typedef __bf16 bf16x8 __attribute__((ext_vector_type(8)));
typedef float f32x16 __attribute__((ext_vector_type(16)));

#define MFMA32(a, b, c) __builtin_amdgcn_mfma_f32_32x32x16_bf16(a, b, c, 0, 0, 0)

// ---------------- one-time weight conversion (verified r4-r11) ------------
// W1t [128 j][1024 i] bf16 (for gemm_A).
// W2B frag-major (C-pass A-operand): idx = ((jt*64+s)*64+lane)*8+e
//     element = W2[jt*32+(lane&31)][s*16+(lane>>5)*8+e]   (0 if k>=1000)
// W2T frag-major (D-pass A-operand): idx = ((kt*8+js)*64+lane)*8+e
//     element = W2[js*16+(lane>>5)*8+e][kt*32+(lane&31)]  (0 if k>=1000)
__global__ __launch_bounds__(256) void prep_weights(
    const float* __restrict__ W1, const float* __restrict__ W2,
    bf16_t* __restrict__ W1t, bf16_t* __restrict__ W2B, bf16_t* __restrict__ W2T) {
  int idx = blockIdx.x * 256 + threadIdx.x;
  if (idx < 131072) {
    { int j = idx >> 10, i = idx & 1023; W1t[idx] = (bf16_t)W1[i * 128 + j]; }
    { int e = idx & 7, l = (idx >> 3) & 63, s = (idx >> 9) & 63, jt = idx >> 15;
      int j = jt * 32 + (l & 31), k = s * 16 + (l >> 5) * 8 + e;
      W2B[idx] = (bf16_t)((k < 1000) ? W2[j * 1000 + k] : 0.f); }
    { int e = idx & 7, l = (idx >> 3) & 63, js = (idx >> 9) & 7, kt = idx >> 12;
      int k = kt * 32 + (l & 31), j = js * 16 + (l >> 5) * 8 + e;
      W2T[idx] = (bf16_t)((k < 1000) ? W2[j * 1000 + k] : 0.f); }
  }
}

// ---------------- A = x @ W1 (f32 out), 256 blocks (verified r8-r11) ------
__global__ __launch_bounds__(256) void gemm_A(
    const float* __restrict__ x, const bf16_t* __restrict__ W1t,
    float* __restrict__ A) {
  int lane = threadIdx.x & 63, w = threadIdx.x >> 6;
  int lo = lane & 31, hi = lane >> 5;
  int row0 = blockIdx.x * 32;
  f32x16 acc = {};
  int kg = hi * 8;
  const float* xrow = x + (size_t)(row0 + lo) * 1024 + kg;
  const bf16_t* b0 = W1t + ((w * 32 + lo) << 10) + kg;
#pragma unroll 4
  for (int ks = 0; ks < 64; ++ks) {
    float xv[8];
    *(float4*)&xv[0] = *(const float4*)(xrow + ks * 16);
    *(float4*)&xv[4] = *(const float4*)(xrow + ks * 16 + 4);
    bf16x8 a;
#pragma unroll
    for (int i = 0; i < 8; ++i) a[i] = (bf16_t)xv[i];
    bf16x8 f0 = *(const bf16x8*)(b0 + ks * 16);
    acc = MFMA32(a, f0, acc);
  }
#pragma unroll
  for (int reg = 0; reg < 16; ++reg) {
    int r = (reg & 3) + 8 * (reg >> 2) + 4 * hi;
    A[(size_t)(row0 + r) * 128 + w * 32 + lo] = acc[reg];
  }
}

// state update: n = clip(v - eps*rho'*(v - u)); JAX clip tie-grad 0.5 at {0,1}
__device__ __forceinline__ bf16x4_t upd4(bf16x4_t v4, const float* u) {
  bf16x4_t n4;
#pragma unroll
  for (int r = 0; r < 4; ++r) {
    float v = (float)v4[r];
    float g = __builtin_fmaf(v, v, -v);          // 0 iff v in {0,1}
    float st = (g == 0.f) ? 0.25f : 0.5f;        // eps * rho'
    float n = __builtin_fmaf(-st, v - u[r], v);
    n4[r] = (bf16_t)__builtin_amdgcn_fmed3f(n, 0.f, 1.f);
  }
  return n4;
}

// ---------------- persistent relaxation + log_softmax ----------------
// 256 blocks x 512 threads = 8 waves, 1 block/CU -> 2 waves/SIMD -> 256
// regs/wave (the key change: r4-r11 ran 16 waves = 128 regs/wave, forcing
// either scratch spill or AGPR-shuttle VALU tax; 8 waves doubles per-wave
// registers at identical per-CU capacity). Frag-major LDS state, o+h
// double-buffered, ONE barrier/iter. Waves 0-3 (C): full-K j-tile jt=w;
// 32 k-steps resident (128 regs) + 32 streamed (8x4 parity, r4-proven);
// uh = A+b_h hoisted. Waves 4-7 (D): 8 ktiles each; 4 resident (128 regs)
// + 4 streamed at-use in half-batches. Peak liveness C~200, D~210 of 256.
__global__ __launch_bounds__(512, 2) void eqprop(
    const float* __restrict__ h0, const float* __restrict__ o0,
    const float* __restrict__ b_h, const float* __restrict__ b_o,
    const float* __restrict__ A, const bf16_t* __restrict__ W2B,
    const bf16_t* __restrict__ W2T, const int* __restrict__ nit,
    float* __restrict__ out) {
  __shared__ __align__(16) char ob[2][65536];   // o state, frag-major
  __shared__ __align__(16) char hb[2][8192];    // h state, frag-major
  __shared__ float bo_lds[1024];

  const int tid = threadIdx.x, lane = tid & 63, w = tid >> 6;
  const int lo = lane & 31, hi = lane >> 5;
  const int row0 = blockIdx.x * 32;

  // ---- init buffer 0 (frag-major) + bo table
  for (int idx = tid; idx < 32768; idx += 512) {
    int b = idx >> 10, k = idx & 1023;
    float v = (k < 1000) ? o0[(size_t)(row0 + b) * 1000 + k] : 0.f;
    int ad = ((k >> 4) << 10) + ((((k >> 3) & 1) << 5) + b) * 16 + ((k & 7) << 1);
    *(bf16_t*)(&ob[0][0] + ad) = (bf16_t)v;
  }
  for (int idx = tid; idx < 4096; idx += 512) {
    int b = idx >> 7, j = idx & 127;
    int ad = ((j >> 4) << 10) + ((((j >> 3) & 1) << 5) + b) * 16 + ((j & 7) << 1);
    *(bf16_t*)(&hb[0][0] + ad) = (bf16_t)h0[(size_t)(row0 + b) * 128 + j];
  }
  for (int idx = tid; idx < 1024; idx += 512)
    bo_lds[idx] = (idx < 1000) ? b_o[idx] : 0.f;

  const int T = nit[0];
  int p = 0;
  __syncthreads();

  if (w < 4) {
    // ============ C-waves: Ct[j,b] = sum_k W2[j,k] o[b,k], jt = w =========
    const int jt = w;
    const bf16_t* WB = W2B + (size_t)jt * 32768 + lane * 8;
#define CW(s) (*(const bf16x8*)(WB + (s) * 512))
    bf16x8 wres[32];                     // k-steps 0..31 resident (128 regs)
#pragma unroll
    for (int s = 0; s < 32; ++s) wres[s] = CW(s);
    float uh[16];                        // b_h + A (iteration-invariant)
#pragma unroll
    for (int q = 0; q < 4; ++q) {
      const int jb = jt * 32 + q * 8 + 4 * hi;
      float4 a4 = *(const float4*)(A + (size_t)(row0 + lo) * 128 + jb);
      float4 b4 = *(const float4*)(b_h + jb);
      uh[q * 4 + 0] = a4.x + b4.x; uh[q * 4 + 1] = a4.y + b4.y;
      uh[q * 4 + 2] = a4.z + b4.z; uh[q * 4 + 3] = a4.w + b4.w;
    }

    for (int t = 0; t < T; ++t) {
      const char* obase = &ob[p][0] + lane * 16;
#define OF(s) (*(const bf16x8*)(obase + (s) * 1024))
      f32x16 acc = {};
#pragma unroll
      for (int s = 0; s < 32; ++s) acc = MFMA32(wres[s], OF(s), acc);
      // streamed k-steps 32..63: 8 batches of 4, unroll-1 parity (r4 shape)
      bf16x8 cs0[4], cs1[4];
      cs0[0] = CW(32); cs0[1] = CW(33); cs0[2] = CW(34); cs0[3] = CW(35);
#pragma unroll 1
      for (int c = 0; c < 8; ++c) {
        const int s0 = 32 + c * 4;
        if ((c & 1) == 0) {
          if (c < 7) {
            cs1[0] = CW(s0 + 4); cs1[1] = CW(s0 + 5);
            cs1[2] = CW(s0 + 6); cs1[3] = CW(s0 + 7);
          }
          acc = MFMA32(cs0[0], OF(s0 + 0), acc);
          acc = MFMA32(cs0[1], OF(s0 + 1), acc);
          acc = MFMA32(cs0[2], OF(s0 + 2), acc);
          acc = MFMA32(cs0[3], OF(s0 + 3), acc);
        } else {
          if (c < 7) {
            cs0[0] = CW(s0 + 4); cs0[1] = CW(s0 + 5);
            cs0[2] = CW(s0 + 6); cs0[3] = CW(s0 + 7);
          }
          acc = MFMA32(cs1[0], OF(s0 + 0), acc);
          acc = MFMA32(cs1[1], OF(s0 + 1), acc);
          acc = MFMA32(cs1[2], OF(s0 + 2), acc);
          acc = MFMA32(cs1[3], OF(s0 + 3), acc);
        }
      }
      // ---- h-update: lane owns b=lo, j = jt*32 + q*8 + 4*hi + r
      const char* hrd = &hb[p][0] + lo * 16 + hi * 8;
      char* hwr = &hb[p ^ 1][0] + lo * 16 + hi * 8;
#pragma unroll
      for (int q = 0; q < 4; ++q) {
        const int boff = (jt * 2 + (q >> 1)) * 1024 + (q & 1) * 512;
        float u[4];
#pragma unroll
        for (int r = 0; r < 4; ++r) u[r] = uh[q * 4 + r] + acc[q * 4 + r];
        bf16x4_t v4 = *(const bf16x4_t*)(hrd + boff);
        *(bf16x4_t*)(hwr + boff) = upd4(v4, u);
      }
      __syncthreads();
      p ^= 1;
    }
  } else {
    // ============ D-waves: Dt[k,b] = sum_j W2[j,k] h[b,j] =================
    const int wd = w - 4;                 // 0..3, owns ktiles wd*8 .. wd*8+7
    const int ktbase = wd * 8;
    const bf16_t* WT = W2T + (size_t)ktbase * 4096 + lane * 8;  // frag-major
    bf16x8 wres[32];                      // ktiles +0..+3 resident (128 regs)
#pragma unroll
    for (int f = 0; f < 32; ++f) wres[f] = *(const bf16x8*)(WT + f * 512);

    for (int t = 0; t < T; ++t) {
      const char* hp = &hb[p][0] + lane * 16;
      const char* ord = &ob[p][0] + lo * 16 + hi * 8;
      char* owr = &ob[p ^ 1][0] + lo * 16 + hi * 8;
      bf16x8 hf[8];
#pragma unroll
      for (int js = 0; js < 8; ++js)
        hf[js] = *(const bf16x8*)(hp + js * 1024);

      // ---- resident ktiles +0..+3
#pragma unroll
      for (int i = 0; i < 4; ++i) {
        f32x16 acc = {};
#pragma unroll
        for (int js = 0; js < 8; ++js)
          acc = MFMA32(wres[i * 8 + js], hf[js], acc);
        const int kt = ktbase + i;
#pragma unroll
        for (int q = 0; q < 4; ++q) {
          const int boff = (kt * 2 + (q >> 1)) * 1024 + (q & 1) * 512;
          float u[4];
          *(float4*)u = *(const float4*)(bo_lds + kt * 32 + q * 8 + 4 * hi);
#pragma unroll
          for (int r = 0; r < 4; ++r) u[r] += acc[q * 4 + r];
          bf16x4_t v4 = *(const bf16x4_t*)(ord + boff);
          *(bf16x4_t*)(owr + boff) = upd4(v4, u);
        }
      }
      // ---- streamed ktiles +4..+7 (at-use, half-batch staging)
#pragma unroll 1
      for (int kl = 4; kl < 8; ++kl) {
        const bf16_t* wt = WT + (size_t)kl * 4096;
        f32x16 acc = {};
        {
          bf16x8 s0 = *(const bf16x8*)(wt + 0 * 512);
          bf16x8 s1 = *(const bf16x8*)(wt + 1 * 512);
          bf16x8 s2 = *(const bf16x8*)(wt + 2 * 512);
          bf16x8 s3 = *(const bf16x8*)(wt + 3 * 512);
          acc = MFMA32(s0, hf[0], acc);
          acc = MFMA32(s1, hf[1], acc);
          acc = MFMA32(s2, hf[2], acc);
          acc = MFMA32(s3, hf[3], acc);
        }
        {
          bf16x8 s4 = *(const bf16x8*)(wt + 4 * 512);
          bf16x8 s5 = *(const bf16x8*)(wt + 5 * 512);
          bf16x8 s6 = *(const bf16x8*)(wt + 6 * 512);
          bf16x8 s7 = *(const bf16x8*)(wt + 7 * 512);
          acc = MFMA32(s4, hf[4], acc);
          acc = MFMA32(s5, hf[5], acc);
          acc = MFMA32(s6, hf[6], acc);
          acc = MFMA32(s7, hf[7], acc);
        }
        const int kt = ktbase + kl;
#pragma unroll
        for (int q = 0; q < 4; ++q) {
          const int boff = (kt * 2 + (q >> 1)) * 1024 + (q & 1) * 512;
          float u[4];
          *(float4*)u = *(const float4*)(bo_lds + kt * 32 + q * 8 + 4 * hi);
#pragma unroll
          for (int r = 0; r < 4; ++r) u[r] += acc[q * 4 + r];
          bf16x4_t v4 = *(const bf16x4_t*)(ord + boff);
          *(bf16x4_t*)(owr + boff) = upd4(v4, u);
        }
      }
      __syncthreads();
      p ^= 1;
    }
  }
  __syncthreads();

  // ---- epilogue: log_softmax per row (4 rows per wave)
  const char* of = &ob[p][0];
  for (int row = w * 4; row < w * 4 + 4; ++row) {
    float m = -1e30f;
    for (int k = lane; k < 1000; k += 64) {
      int ad = ((k >> 4) << 10) + ((((k >> 3) & 1) << 5) + row) * 16 + ((k & 7) << 1);
      m = fmaxf(m, (float)*(const bf16_t*)(of + ad));
    }
#pragma unroll
    for (int s = 32; s > 0; s >>= 1) m = fmaxf(m, __shfl_xor(m, s));
    float sum = 0.f;
    for (int k = lane; k < 1000; k += 64) {
      int ad = ((k >> 4) << 10) + ((((k >> 3) & 1) << 5) + row) * 16 + ((k & 7) << 1);
      sum += expf((float)*(const bf16_t*)(of + ad) - m);
    }
#pragma unroll
    for (int s = 32; s > 0; s >>= 1) sum += __shfl_xor(sum, s);
    float lse = m + logf(sum);
    for (int k = lane; k < 1000; k += 64) {
      int ad = ((k >> 4) << 10) + ((((k >> 3) & 1) << 5) + row) * 16 + ((k & 7) << 1);
      out[(size_t)(row0 + row) * 1000 + k] =
          (float)*(const bf16_t*)(of + ad) - lse;
    }
  }
}

extern "C" void kernel_launch(void* const* d_in, const int* in_sizes, int n_in,
                              void* d_out, int out_size, void* d_ws, size_t ws_size,
                              hipStream_t stream) {
  const float* x   = (const float*)d_in[0];
  const float* h0  = (const float*)d_in[1];
  const float* o0  = (const float*)d_in[2];
  // d_in[3] = b_in: unused by the h/o gradients
  const float* b_h = (const float*)d_in[4];
  const float* b_o = (const float*)d_in[5];
  const float* W1  = (const float*)d_in[6];
  const float* W2  = (const float*)d_in[7];
  const int*   nit = (const int*)d_in[8];
  float* out = (float*)d_out;

  char* ws = (char*)d_ws;
  float*  A   = (float*)ws;                           // 8192*128*4 = 4 MB
  bf16_t* W1t = (bf16_t*)(ws + 4194304);              // 256 KB
  bf16_t* W2B = (bf16_t*)(ws + 4194304 + 262144);     // 256 KB
  bf16_t* W2T = (bf16_t*)(ws + 4194304 + 524288);     // 256 KB

  prep_weights<<<512, 256, 0, stream>>>(W1, W2, W1t, W2B, W2T);
  gemm_A<<<256, 256, 0, stream>>>(x, W1t, A);
  eqprop<<<256, 512, 0, stream>>>(h0, o0, b_h, b_o, A, W2B, W2T, nit, out);
}